// Round 5
// baseline (1219.201 us; speedup 1.0000x reference)
//
#include <hip/hip_runtime.h>
#include <hip/hip_bf16.h>

#define BSZ    256
#define SEQT   2048
#define NVOCAB 10
#define DEMB   32
#define G4     256
#define BLK    512   // 8 waves: wave = (chain = wv>>2, gate = wv&3); lane = unit

typedef unsigned short u16;
typedef unsigned int   u32;
typedef float    v4f __attribute__((ext_vector_type(4)));
typedef u32      v4u __attribute__((ext_vector_type(4)));
typedef _Float16 v2h __attribute__((ext_vector_type(2)));

// ws layout (float slots; some regions hold u32 f16-pair bits)
#define FLAG_OFF 0
#define XZ4_OFF  4                      // [10 v][64 j][4 g] f32 = 2560 (16B aligned)
#define WHP_OFF  (XZ4_OFF + 2560)      // u32 [64 l][4 g][32 kpair] = 8192
#define W1P_OFF  (WHP_OFF + 8192)      // u32 [64 o][64 kpair] = 4096
#define W2P_OFF  (W1P_OFF + 4096)      // u32 [32 o][32 kpair] = 1024
#define W3_OFF   (W2P_OFF + 1024)      // f32 [32][10] = 320
#define B1_OFF   (W3_OFF + 320)
#define B2_OFF   (B1_OFF + 64)
#define B3_OFF   (B2_OFF + 32)

__device__ __forceinline__ float bf2f(u16 x) {
    union { u32 u; float f; } v; v.u = ((u32)x) << 16; return v.f;
}
__device__ __forceinline__ u16 f2bf(float f) {
    union { float f; u32 u; } v; v.f = f;
    u32 r = v.u + 0x7fff + ((v.u >> 16) & 1);
    return (u16)(r >> 16);
}
__device__ __forceinline__ float ldw(const void* p, int i, bool isbf) {
    return isbf ? bf2f(((const u16*)p)[i]) : ((const float*)p)[i];
}
__device__ __forceinline__ float frcp(float x) { return __builtin_amdgcn_rcpf(x); }
__device__ __forceinline__ float sigf(float z) { return frcp(1.f + __expf(-z)); }  // inf-safe
__device__ __forceinline__ u16 f2h(float x) {
    union { _Float16 h; u16 u; } v; v.h = (_Float16)x; return v.u;
}
__device__ __forceinline__ u32 packh2(float lo, float hi) {
    return (u32)f2h(lo) | ((u32)f2h(hi) << 16);
}
__device__ __forceinline__ float fdot2f(u32 a, u32 b, float c) {
    union { u32 u; v2h h; } ua, ub; ua.u = a; ub.u = b;
    return __builtin_amdgcn_fdot2(ua.h, ub.h, c, false);
}
// 4 f16-pair dots: acc += w.h (8 MACs), f32 accumulation
__device__ __forceinline__ void dot4(float& acc, v4u w, v4u h) {
    acc = fdot2f(w.x, h.x, acc); acc = fdot2f(w.y, h.y, acc);
    acc = fdot2f(w.z, h.z, acc); acc = fdot2f(w.w, h.w, acc);
}

// One-time prep: dtype detect, xz float4 table (E@Wx+b: 10 rows), per-lane
// f16-packed Wh table, f16-packed MLP weights.  (unchanged)
__global__ void init_kernel(const void* __restrict__ E,  const void* __restrict__ Wx,
                            const void* __restrict__ Wh, const void* __restrict__ bg,
                            const void* __restrict__ W1, const void* __restrict__ b1,
                            const void* __restrict__ W2, const void* __restrict__ b2,
                            const void* __restrict__ W3, const void* __restrict__ b3,
                            float* __restrict__ ws) {
    __shared__ int s_isbf;
    const int tid = threadIdx.x;  // 256 threads, 1 block
    if (tid == 0) s_isbf = 1;
    __syncthreads();
    {   // bf16 data decodes small; fp32 low-halves decode wild exponents
        const u16* Eu = (const u16*)E;
        for (int i = tid; i < NVOCAB * DEMB; i += 256) {
            float v = bf2f(Eu[i]);
            if (!(fabsf(v) < 16.0f)) s_isbf = 0;
        }
    }
    __syncthreads();
    const bool isbf = (s_isbf != 0);
    if (tid == 0) ws[FLAG_OFF] = isbf ? 1.0f : 0.0f;
    u32* wsu = (u32*)ws;

    {   // xz[v][j][g] = b[g*64+j] + sum_d E[v][d]*Wx[d][g*64+j]
        const int g = tid >> 6, j = tid & 63, col = g * 64 + j;
        for (int v = 0; v < NVOCAB; v++) {
            float acc = ldw(bg, col, isbf);
            #pragma unroll
            for (int d = 0; d < DEMB; d++)
                acc += ldw(E, v * DEMB + d, isbf) * ldw(Wx, d * G4 + col, isbf);
            ws[XZ4_OFF + (v * 64 + j) * 4 + g] = acc;
        }
    }
    // Wh per-lane table: u32[l*128 + g*32 + kk] = pack(Wh[2kk][g*64+l], Wh[2kk+1][g*64+l])
    for (int i = tid; i < 8192; i += 256) {
        int l = i >> 7, rem = i & 127, g = rem >> 5, kk = rem & 31;
        int col = g * 64 + l;
        wsu[WHP_OFF + i] = packh2(ldw(Wh, (2 * kk) * G4 + col, isbf),
                                  ldw(Wh, (2 * kk + 1) * G4 + col, isbf));
    }
    for (int i = tid; i < 4096; i += 256) {   // W1 [128][64] -> [o][kpair] f16x2
        int o = i >> 6, kk = i & 63;
        wsu[W1P_OFF + i] = packh2(ldw(W1, (2 * kk) * 64 + o, isbf),
                                  ldw(W1, (2 * kk + 1) * 64 + o, isbf));
    }
    for (int i = tid; i < 1024; i += 256) {   // W2 [64][32] -> [o][kpair]
        int o = i >> 5, kk = i & 31;
        wsu[W2P_OFF + i] = packh2(ldw(W2, (2 * kk) * 32 + o, isbf),
                                  ldw(W2, (2 * kk + 1) * 32 + o, isbf));
    }
    for (int i = tid; i < 320; i += 256) ws[W3_OFF + i] = ldw(W3, i, isbf);
    if (tid < 64) ws[B1_OFF + tid] = ldw(b1, tid, isbf);
    if (tid < 32) ws[B2_OFF + tid] = ldw(b2, tid, isbf);
    if (tid < NVOCAB) ws[B3_OFF + tid] = ldw(b3, tid, isbf);
}

// Gate-parallel recurrence: 1 block (512 thr, 8 waves) per batch element.
//   wave wv: chain ch = wv>>2, gate g = wv&3 (0=i,1=f,2=g~,3=o); lane = unit.
// Per-wave persistent weights = one 64x64 gate block = 8 quads = 32 VGPRs
// (fits the backend's ~84-reg budget -> no AGPR demotion/shuttles, which
// cost ~500 junk VALU cyc/step in the 1-wave-per-chain design: VGPR stuck
// at 84 across launch_bounds/waves_per_eu/num_vgpr attempts).
// Per step: read own private h (same-wave LDS, no barrier), 32 fdot2,
// own activation, write acts[parity][ch][g][lane], ONE __syncthreads,
// read 4 acts, redundantly update c (identical across the 4 waves),
// write private h; g==0 also writes canonical hwinh row for the MLP.
// MLP: all 8 waves, 4 tokens each, serialized at window boundaries.
__global__ __launch_bounds__(BLK) void lstm_fused(
    const int* __restrict__ num1, const int* __restrict__ num2,
    const float* __restrict__ ws, void* __restrict__ outv)
{
    __shared__ __align__(16) float xzg[4 * 10 * 64];    // [g][v][j] 10240 B
    __shared__ __align__(16) u16 hwinh[2][32][128];     // 16384 B (canonical h, dbuf)
    __shared__ __align__(16) u16 hpriv[8][64];          //  1024 B (per-wave h copy)
    __shared__ __align__(16) float acts[2][2][4][64];   //  4096 B [parity][ch][gate][unit]
    __shared__ __align__(16) u32 W1p[64 * 68];          // 17408 B
    __shared__ __align__(16) u32 W2p[32 * 36];          //  4608 B
    __shared__ float W3s[320];                          //  1280 B
    __shared__ float B1s[64], B2s[32], B3s[16];         //   448 B
    __shared__ __align__(16) u16 w1h[32 * 72];          //  4608 B
    __shared__ __align__(16) float w2buf[32 * 36];      //  4608 B
    __shared__ int idxs[2][2][32];                      //   512 B  -> 65216 B total

    const int tid = threadIdx.x, bb = blockIdx.x;
    const int wv = tid >> 6, l = tid & 63;
    const int ch = wv >> 2, g = wv & 3;
    const u32* wsu = (const u32*)ws;
    const bool outbf = (ws[FLAG_OFF] != 0.0f);

    // ---- staging ----
    for (int t = tid; t < 2560; t += BLK) {             // transpose xz to [g][v][j]
        int gg = t / 640, rem = t - gg * 640;
        xzg[t] = ws[XZ4_OFF + rem * 4 + gg];
    }
    for (int i = tid; i < 4096; i += BLK) { int o = i >> 6, kk = i & 63; W1p[o * 68 + kk] = wsu[W1P_OFF + i]; }
    for (int i = tid; i < 1024; i += BLK) { int o = i >> 5, kk = i & 31; W2p[o * 36 + kk] = wsu[W2P_OFF + i]; }
    for (int i = tid; i < 320; i += BLK) W3s[i] = ws[W3_OFF + i];
    if (tid < 64) B1s[tid] = ws[B1_OFF + tid];
    if (tid < 32) B2s[tid] = ws[B2_OFF + tid];
    if (tid < NVOCAB) B3s[tid] = ws[B3_OFF + tid];
    hpriv[wv][l] = 0;                                   // h_{-1} = 0 (all 8 waves)
    if (tid < 64) { int c0 = tid >> 5, tt = tid & 31;
                    idxs[0][c0][tt] = (c0 == 0 ? num1 : num2)[bb * SEQT + tt]; }

    // persistent per-wave weights: gate g's 64x64 block, kpairs 0..31
    const v4u* whsrc = (const v4u*)(wsu + WHP_OFF) + ((size_t)l * 32 + g * 8);
    v4u wqA0 = whsrc[0], wqA1 = whsrc[1], wqA2 = whsrc[2], wqA3 = whsrc[3];
    v4u wqB0 = whsrc[4], wqB1 = whsrc[5], wqB2 = whsrc[6], wqB3 = whsrc[7];
    float c = 0.f;

    // MLP constants (cheap, recomputed from LDS inside MLP phase)
    const int tb = wv * 4;                              // 4 tokens per wave
    const int th = l >> 5, o2 = l & 31;
    const int tloc = l / 10, o3 = l - tloc * 10;
    u16* outb = (u16*)outv; float* outf = (float*)outv;

    __syncthreads();

    for (int win = 0; win <= 64; win++) {
        // keep weight quads live in VGPRs across the backedge
        #define PINQ(x) asm("" : "+v"(x))
        PINQ(wqA0); PINQ(wqA1); PINQ(wqA2); PINQ(wqA3);
        PINQ(wqB0); PINQ(wqB1); PINQ(wqB2); PINQ(wqB3);
        #undef PINQ
        if (win < 64) {
            const int wb = win & 1;
            if (win < 63 && g == 3 && l < 32)           // o-waves prefetch next idx window
                idxs[(win + 1) & 1][ch][l] =
                    (ch == 0 ? num1 : num2)[bb * SEQT + (win + 1) * 32 + l];
            #pragma unroll 1
            for (int tt = 0; tt < 32; tt++) {
                const int p = tt & 1;
                const int idx = idxs[wb][ch][tt];
                const v4u* hp = (const v4u*)&hpriv[wv][0];   // own copy, same-wave order
                float za = 0.f, zb = 0.f;
                {
                    v4u h0 = hp[0], h1 = hp[1], h2 = hp[2], h3 = hp[3];
                    dot4(za, wqA0, h0); dot4(za, wqA1, h1);
                    dot4(za, wqA2, h2); dot4(za, wqA3, h3);
                }
                {
                    v4u h4 = hp[4], h5 = hp[5], h6 = hp[6], h7 = hp[7];
                    dot4(zb, wqB0, h4); dot4(zb, wqB1, h5);
                    dot4(zb, wqB2, h6); dot4(zb, wqB3, h7);
                }
                float z = za + zb + xzg[g * 640 + idx * 64 + l];
                float act = (g == 2) ? (2.f * sigf(2.f * z) - 1.f)   // tanh
                                     : sigf(z);
                acts[p][ch][g][l] = act;
                __syncthreads();                        // acts visible block-wide
                float ai = acts[p][ch][0][l], af = acts[p][ch][1][l];
                float ag = acts[p][ch][2][l], ao = acts[p][ch][3][l];
                c = af * c + ai * ag;                   // redundant, identical in 4 waves
                float thh = 1.f - 2.f * frcp(__expf(2.f * c) + 1.f);  // inf-safe tanh
                u16 hb = f2h(ao * thh);
                hpriv[wv][l] = hb;                      // own copy for next step
                if (g == 0) hwinh[wb][tt][ch * 64 + l] = hb;  // canonical (for MLP)
            }
        }
        __syncthreads();                                // window's hwinh complete
        if (win >= 1) {
            // -------- MLP for window win-1: all 8 waves, tokens [tb, tb+4) ------
            const int pw = win - 1, pwb = pw & 1;
            const float b1o = B1s[l];
            // L1: relu(b1 + hwin[tk][:128] . W1[:,l]), 4 tokens/wave
            float acc0 = b1o, acc1 = b1o, acc2 = b1o, acc3 = b1o;
            for (int kc = 0; kc < 16; kc++) {
                v4u wq = *(const v4u*)&W1p[l * 68 + 4 * kc];
                v4u q0 = *(const v4u*)&hwinh[pwb][tb + 0][8 * kc];
                v4u q1 = *(const v4u*)&hwinh[pwb][tb + 1][8 * kc];
                v4u q2 = *(const v4u*)&hwinh[pwb][tb + 2][8 * kc];
                v4u q3 = *(const v4u*)&hwinh[pwb][tb + 3][8 * kc];
                dot4(acc0, wq, q0); dot4(acc1, wq, q1);
                dot4(acc2, wq, q2); dot4(acc3, wq, q3);
            }
            w1h[(tb + 0) * 72 + l] = f2h(fmaxf(acc0, 0.f));
            w1h[(tb + 1) * 72 + l] = f2h(fmaxf(acc1, 0.f));
            w1h[(tb + 2) * 72 + l] = f2h(fmaxf(acc2, 0.f));
            w1h[(tb + 3) * 72 + l] = f2h(fmaxf(acc3, 0.f));
            // L2: rows tb+2*th+{0,1}, same-wave LDS ordering (no barrier)
            const float b2o = B2s[o2];
            float a20 = b2o, a21 = b2o;
            for (int kc = 0; kc < 8; kc++) {
                v4u wq = *(const v4u*)&W2p[o2 * 36 + 4 * kc];
                v4u q0 = *(const v4u*)&w1h[(tb + th * 2 + 0) * 72 + 8 * kc];
                v4u q1 = *(const v4u*)&w1h[(tb + th * 2 + 1) * 72 + 8 * kc];
                dot4(a20, wq, q0); dot4(a21, wq, q1);
            }
            w2buf[(tb + th * 2 + 0) * 36 + o2] = fmaxf(a20, 0.f);
            w2buf[(tb + th * 2 + 1) * 36 + o2] = fmaxf(a21, 0.f);
            // L3: 4 tokens x 10 outputs = 40 lanes, 1 output each
            if (l < 40) {
                float w3r[32];
                #pragma unroll
                for (int k = 0; k < 32; k++) w3r[k] = W3s[k * 10 + o3];
                const int tk = tb + tloc;
                const v4f* wp = (const v4f*)&w2buf[tk * 36];
                float a = B3s[o3];
                #pragma unroll
                for (int q = 0; q < 8; q++) {
                    v4f w4 = wp[q];
                    a += w3r[4 * q]     * w4.x + w3r[4 * q + 1] * w4.y
                       + w3r[4 * q + 2] * w4.z + w3r[4 * q + 3] * w4.w;
                }
                const size_t oi = (size_t)(bb * SEQT + pw * 32 + tk) * NVOCAB + o3;
                if (outbf) outb[oi] = f2bf(a); else outf[oi] = a;
            }
        }
        __syncthreads();                                // MLP reads done before reuse
    }
}

extern "C" void kernel_launch(void* const* d_in, const int* in_sizes, int n_in,
                              void* d_out, int out_size, void* d_ws, size_t ws_size,
                              hipStream_t stream) {
    const int* num1 = (const int*)d_in[0];
    const int* num2 = (const int*)d_in[1];
    float* ws = (float*)d_ws;

    hipLaunchKernelGGL(init_kernel, dim3(1), dim3(256), 0, stream,
                       d_in[2], d_in[3], d_in[4], d_in[5], d_in[6], d_in[7],
                       d_in[8], d_in[9], d_in[10], d_in[11], ws);
    hipLaunchKernelGGL(lstm_fused, dim3(BSZ), dim3(BLK), 0, stream,
                       num1, num2, ws, d_out);
}